// Round 3
// baseline (223.049 us; speedup 1.0000x reference)
//
#include <hip/hip_runtime.h>

// EuclideanFastAttention — MI355X (gfx950)
// A = (1/6) qr·kr^T per batch (256x256, K=6912, split-K=12), out = A·v.

typedef unsigned short u16;
typedef __attribute__((ext_vector_type(8))) short short8;   // 8 x bf16 bits (MFMA frag)
typedef __attribute__((ext_vector_type(4))) float f32x4;    // MFMA acc
typedef __attribute__((ext_vector_type(4))) unsigned short u16x4;

static constexpr int N_NODES = 4096;
static constexpr int NBATCH  = 16;
static constexpr int NB      = 256;
static constexpr int NDEG    = 9;
static constexpr int MD      = NDEG * 128;    // 1152
static constexpr int KTOT    = 6 * MD;        // 6912
static constexpr int NSLICE  = 12;            // split-K slices of 576

// ws layout (bytes), aliased along the kernel timeline
static constexpr size_t OFF_CS  = 0;                                  // 4096*192 float2 = 6.29MB
static constexpr size_t OFF_WT  = OFF_CS  + (size_t)N_NODES*192*8;    // 9*16384 bf16
static constexpr size_t OFF_QR  = OFF_WT  + (size_t)9*16384*2;        // 56.6MB
static constexpr size_t OFF_KR  = OFF_QR  + (size_t)N_NODES*KTOT*2;   // 56.6MB
static constexpr size_t OFF_VT  = OFF_KR  + (size_t)N_NODES*KTOT*2;   // 9.4MB
static constexpr size_t OFF_VBF = OFF_VT  + (size_t)N_NODES*MD*2;     // 9.4MB (dead after transv)
static constexpr size_t OFF_AP  = OFF_VBF;                            // 12*16*65536 bf16 = 25.2MB (overlaps vbf)
static constexpr size_t OFF_ABF = OFF_QR;                             // 2MB (overlaps qr, written post-gemm1)
// high-water = OFF_AP + 25.2MB = 147.3MB  (< 149.2MB proven in R1)

__device__ inline u16 f2bf(float x) {
    union { float f; unsigned u; } v; v.f = x;
    unsigned r = v.u + 0x7fffu + ((v.u >> 16) & 1u);   // RNE
    return (u16)(r >> 16);
}
__device__ inline float bf2f(u16 h) {
    union { unsigned u; float f; } v; v.u = ((unsigned)h) << 16; return v.f;
}

// ---------------- kernel 1: trig table + W transpose (merged) ----------------
__global__ __launch_bounds__(256) void k_prep(const float* __restrict__ pos,
                                              float2* __restrict__ cs,
                                              const float* __restrict__ Wq,
                                              const float* __restrict__ Wk,
                                              const float* __restrict__ Wv,
                                              u16* __restrict__ wt) {
    int bx = blockIdx.x, tid = threadIdx.x;
    if (bx < 3072) {                      // trig: cs[n][dim][i] = (cos,sin)(pos*theta_i)
        int idx = bx * 256 + tid;         // N*192
        int n = idx / 192, r = idx % 192;
        int gp = r >> 6, i = r & 63;
        float p = pos[n * 3 + gp];
        float theta = (float)i * (8.0f / (63.0f * 10.0f));
        float s, c;
        sincosf(p * theta, &s, &c);
        cs[idx] = make_float2(c, s);
        return;
    }
    // W transpose+cast: wt[(mat*3+l)][j][f] = W[l][f][j]
    int t = bx - 3072;                    // 0..35
    int blk = t >> 2, tt = t & 3;
    int mat = blk / 3, l = blk % 3;
    const float* W = (mat == 0 ? Wq : (mat == 1 ? Wk : Wv)) + (size_t)l * 16384;
    int j0 = (tt >> 1) * 64, f0 = (tt & 1) * 64;
    __shared__ u16 tile[64 * 72];
    for (int e = tid; e < 1024; e += 256) {
        int r = e >> 4, c = e & 15;
        float4 wv = *(const float4*)(W + (size_t)(f0 + r) * 128 + j0 + c * 4);
        tile[(c * 4 + 0) * 72 + r] = f2bf(wv.x);
        tile[(c * 4 + 1) * 72 + r] = f2bf(wv.y);
        tile[(c * 4 + 2) * 72 + r] = f2bf(wv.z);
        tile[(c * 4 + 3) * 72 + r] = f2bf(wv.w);
    }
    __syncthreads();
    u16* dst = wt + (size_t)blk * 16384;
    for (int e = tid; e < 512; e += 256) {
        int j = e >> 3, c = e & 7;
        *(uint4*)(dst + (size_t)(j0 + j) * 128 + f0 + c * 8) = *(const uint4*)(tile + j * 72 + c * 8);
    }
}

// ---------------- kernel 2: fused dense(q,k,v) + bias + RoPE -----------------
// grid (64 node-tiles, 9 m).  X staged once; loop mats q,k,v.
__global__ __launch_bounds__(256) void k_qkv(const float* __restrict__ X,
                                             const u16* __restrict__ wt,
                                             const float* __restrict__ bq,
                                             const float* __restrict__ bk,
                                             const float* __restrict__ bv,
                                             const float2* __restrict__ cs,
                                             u16* __restrict__ qr,
                                             u16* __restrict__ kr,
                                             u16* __restrict__ vbf) {
    const int nt = blockIdx.x, m = blockIdx.y;
    const int n0 = nt * 64;
    const int deg = (m == 0) ? 0 : (m < 4 ? 1 : 2);
    const int tid = threadIdx.x;

    __shared__ u16 Xs[64 * 136];
    __shared__ u16 Ws[128 * 136];          // restaged per mat; reused as O0/O1
    u16* O0 = Ws;
    u16* O1 = Ws + 64 * 136;

    for (int e = tid; e < 2048; e += 256) {            // stage X once (fp32->bf16)
        int r = e >> 5, f4 = e & 31;
        float4 xv = *(const float4*)(X + (size_t)(n0 + r) * MD + m * 128 + f4 * 4);
        u16x4 o; o.x = f2bf(xv.x); o.y = f2bf(xv.y); o.z = f2bf(xv.z); o.w = f2bf(xv.w);
        *(u16x4*)(Xs + r * 136 + f4 * 4) = o;
    }

    const int w = tid >> 6, lane = tid & 63, quad = lane >> 4, lrow = lane & 15;
    const bool even = !(lrow & 1);

    for (int mat = 0; mat < 3; mat++) {
        __syncthreads();                   // prior epilogue LDS reads done (mat0: no-op)
        const uint4* wsrc = (const uint4*)(wt + (size_t)(mat * 3 + deg) * 16384);
        for (int e = tid; e < 2048; e += 256) {
            int j = e >> 4, f8 = e & 15;
            *(uint4*)(Ws + j * 136 + f8 * 8) = wsrc[j * 16 + f8];
        }
        __syncthreads();

        f32x4 acc[8];
#pragma unroll
        for (int ct = 0; ct < 8; ct++) acc[ct] = (f32x4){0.f, 0.f, 0.f, 0.f};
#pragma unroll
        for (int ks = 0; ks < 4; ks++) {
            short8 a = *(const short8*)(Xs + (w * 16 + lrow) * 136 + ks * 32 + quad * 8);
#pragma unroll
            for (int ct = 0; ct < 8; ct++) {
                short8 bfr = *(const short8*)(Ws + (ct * 16 + lrow) * 136 + ks * 32 + quad * 8);
                acc[ct] = __builtin_amdgcn_mfma_f32_16x16x32_bf16(a, bfr, acc[ct], 0, 0, 0);
            }
        }

        const float* bias = (mat == 0) ? bq : ((mat == 1) ? bk : bv);
        float yv[8][4];
#pragma unroll
        for (int ct = 0; ct < 8; ct++) {
            float bj = (m == 0) ? bias[ct * 16 + lrow] : 0.0f;
#pragma unroll
            for (int r = 0; r < 4; r++) yv[ct][r] = acc[ct][r] + bj;
        }

        if (mat == 2) {                    // v: stage tile, coalesced store
            __syncthreads();
#pragma unroll
            for (int ct = 0; ct < 8; ct++)
#pragma unroll
                for (int r = 0; r < 4; r++) {
                    int nl = w * 16 + quad * 4 + r;
                    O0[nl * 136 + ct * 16 + lrow] = f2bf(yv[ct][r]);
                }
            __syncthreads();
            for (int e = tid; e < 1024; e += 256) {
                int nl = e >> 4, c = e & 15;
                *(uint4*)(vbf + (size_t)(n0 + nl) * MD + m * 128 + c * 8) =
                    *(const uint4*)(O0 + nl * 136 + c * 8);
            }
            continue;
        }

        float pv[8][4];                    // partner feature j^1
#pragma unroll
        for (int ct = 0; ct < 8; ct++)
#pragma unroll
            for (int r = 0; r < 4; r++) pv[ct][r] = __shfl_xor(yv[ct][r], 1);

        u16* dst = (mat == 0) ? qr : kr;
        for (int gp = 0; gp < 3; gp++) {
            __syncthreads();
#pragma unroll
            for (int ct = 0; ct < 8; ct++) {
                int i = ct * 8 + (lrow >> 1);
#pragma unroll
                for (int r = 0; r < 4; r++) {
                    int nl = w * 16 + quad * 4 + r;
                    float2 c_s = cs[((size_t)(n0 + nl) * 3 + gp) * 64 + i];
                    float t1 = yv[ct][r] * c_s.x, t2 = pv[ct][r] * c_s.y;
                    float r0, r1;
                    if (even) { r0 = t1 - t2; r1 = t1 + t2; }
                    else      { r0 = t1 + t2; r1 = t1 - t2; }
                    O0[nl * 136 + ct * 16 + lrow] = f2bf(r0);
                    O1[nl * 136 + ct * 16 + lrow] = f2bf(r1);
                }
            }
            __syncthreads();
            for (int e = tid; e < 1024; e += 256) {
                int nl = e >> 4, c = e & 15;
                size_t o = (size_t)(n0 + nl) * KTOT + (size_t)(gp * 2) * MD + m * 128 + c * 8;
                *(uint4*)(dst + o)      = *(const uint4*)(O0 + nl * 136 + c * 8);
                *(uint4*)(dst + o + MD) = *(const uint4*)(O1 + nl * 136 + c * 8);
            }
        }
    }
}

// ---------------- kernel 3: transpose v -> vt[d][n] --------------------------
__global__ __launch_bounds__(256) void k_transv(const u16* __restrict__ vbf,
                                                u16* __restrict__ vt) {
    int nt = blockIdx.x, dt = blockIdx.y;     // 64 x 18
    __shared__ u16 tile[64 * 65];
    int tid = threadIdx.x;
    for (int e = tid; e < 4096; e += 256) {
        int r = e >> 6, c = e & 63;
        tile[r * 65 + c] = vbf[(size_t)(nt * 64 + r) * MD + dt * 64 + c];
    }
    __syncthreads();
    for (int e = tid; e < 4096; e += 256) {
        int r = e >> 6, c = e & 63;
        vt[(size_t)(dt * 64 + r) * N_NODES + nt * 64 + c] = tile[c * 65 + r];
    }
}

// ---------------- kernel 4: Apart[s] = qr·kr^T slice (256x256, K=576) --------
// grid (16 b, 12 s), 1024 threads. qr/kr each read exactly once.
__global__ __launch_bounds__(1024) void k_gemm1(const u16* __restrict__ qr,
                                                const u16* __restrict__ kr,
                                                u16* __restrict__ Apart) {
    const int b = blockIdx.x, s = blockIdx.y;
    const size_t koff = (size_t)s * 576;
    const int tid = threadIdx.x;
    __shared__ u16 Qs[256 * 72];
    __shared__ u16 Ks[256 * 72];
    const int w = tid >> 6, lane = tid & 63, quad = lane >> 4, lrow = lane & 15;
    const int wr = w >> 1, wc = w & 1;     // wave: rows wr*32(+rt*16), cols wc*128(+ct*16)

    const int lr = tid >> 3, lsc = tid & 7;           // load map: row, 16B-chunk
    uint4 qb[2], kb[2];
    auto loadk = [&](int kc) {
        size_t base = koff + kc * 64 + lsc * 8;
#pragma unroll
        for (int h = 0; h < 2; h++) {
            int r = lr + h * 128;
            qb[h] = *(const uint4*)(qr + (size_t)(b * NB + r) * KTOT + base);
            kb[h] = *(const uint4*)(kr + (size_t)(b * NB + r) * KTOT + base);
        }
    };

    f32x4 acc[2][8];
#pragma unroll
    for (int rt = 0; rt < 2; rt++)
#pragma unroll
        for (int ct = 0; ct < 8; ct++) acc[rt][ct] = (f32x4){0.f, 0.f, 0.f, 0.f};

    loadk(0);
    for (int kc = 0; kc < 9; kc++) {
        __syncthreads();                   // LDS free (prev MFMA reads done)
#pragma unroll
        for (int h = 0; h < 2; h++) {
            *(uint4*)(Qs + (lr + h * 128) * 72 + lsc * 8) = qb[h];
            *(uint4*)(Ks + (lr + h * 128) * 72 + lsc * 8) = kb[h];
        }
        __syncthreads();
        if (kc < 8) loadk(kc + 1);         // prefetch overlaps MFMA below
#pragma unroll
        for (int ks = 0; ks < 2; ks++) {
            short8 a0 = *(const short8*)(Qs + (wr * 32 + lrow) * 72 + ks * 32 + quad * 8);
            short8 a1 = *(const short8*)(Qs + (wr * 32 + 16 + lrow) * 72 + ks * 32 + quad * 8);
#pragma unroll
            for (int ct = 0; ct < 8; ct++) {
                short8 bfr = *(const short8*)(Ks + (wc * 128 + ct * 16 + lrow) * 72 + ks * 32 + quad * 8);
                acc[0][ct] = __builtin_amdgcn_mfma_f32_16x16x32_bf16(a0, bfr, acc[0][ct], 0, 0, 0);
                acc[1][ct] = __builtin_amdgcn_mfma_f32_16x16x32_bf16(a1, bfr, acc[1][ct], 0, 0, 0);
            }
        }
    }
    u16* dst = Apart + ((size_t)s * NBATCH + b) * (NB * NB);
#pragma unroll
    for (int rt = 0; rt < 2; rt++)
#pragma unroll
        for (int ct = 0; ct < 8; ct++)
#pragma unroll
            for (int r = 0; r < 4; r++) {
                int rib = wr * 32 + rt * 16 + quad * 4 + r;
                int cib = wc * 128 + ct * 16 + lrow;
                dst[(size_t)rib * NB + cib] = f2bf(acc[rt][ct][r]);   // L2 merges partial lines
            }
}

// ---------------- kernel 5: A = (1/6) sum_s Apart[s] -------------------------
__global__ __launch_bounds__(256) void k_reduceA(const u16* __restrict__ Ap,
                                                 u16* __restrict__ Abf) {
    int idx = blockIdx.x * 256 + threadIdx.x;     // 131072
    size_t base = (size_t)idx * 8;
    float sacc[8];
#pragma unroll
    for (int i = 0; i < 8; i++) sacc[i] = 0.f;
#pragma unroll
    for (int s = 0; s < NSLICE; s++) {
        uint4 v = *(const uint4*)(Ap + (size_t)s * (NBATCH * NB * NB) + base);
        const unsigned* u = (const unsigned*)&v;
#pragma unroll
        for (int h = 0; h < 4; h++) {
            sacc[h * 2]     += bf2f((u16)(u[h] & 0xffff));
            sacc[h * 2 + 1] += bf2f((u16)(u[h] >> 16));
        }
    }
    const float sc = 1.0f / 6.0f;
    u16 o[8];
#pragma unroll
    for (int i = 0; i < 8; i++) o[i] = f2bf(sacc[i] * sc);
    *(uint4*)(Abf + base) = *(const uint4*)o;
}

// ---------------- kernel 6: out = A · v per batch (+mask) --------------------
__global__ __launch_bounds__(256) void k_gemm2(const u16* __restrict__ Abf,
                                               const u16* __restrict__ vt,
                                               const int* __restrict__ gmask,
                                               float* __restrict__ out) {
    int rt = blockIdx.x, dcb = blockIdx.y, b = blockIdx.z;
    int d0 = dcb * 128;
    int tid = threadIdx.x;
    __shared__ u16 As[64 * 72];
    __shared__ u16 Vs[128 * 72];
    int w = tid >> 6, lane = tid & 63, quad = lane >> 4, lrow = lane & 15;

    f32x4 acc[8];
#pragma unroll
    for (int ct = 0; ct < 8; ct++) acc[ct] = (f32x4){0.f, 0.f, 0.f, 0.f};

    for (int kc = 0; kc < 4; kc++) {
        int k0 = kc * 64;
#pragma unroll
        for (int e = tid; e < 512; e += 256) {
            int r = e >> 3, sc2 = e & 7;
            *(uint4*)(As + r * 72 + sc2 * 8) =
                *(const uint4*)(Abf + (size_t)b * NB * NB + (size_t)(rt * 64 + r) * NB + k0 + sc2 * 8);
        }
#pragma unroll
        for (int e = tid; e < 1024; e += 256) {
            int rr = e >> 3, sc2 = e & 7;
            *(uint4*)(Vs + rr * 72 + sc2 * 8) =
                *(const uint4*)(vt + (size_t)(d0 + rr) * N_NODES + b * NB + k0 + sc2 * 8);
        }
        __syncthreads();
#pragma unroll
        for (int ks = 0; ks < 2; ks++) {
            short8 a = *(const short8*)(As + (w * 16 + lrow) * 72 + ks * 32 + quad * 8);
#pragma unroll
            for (int ct = 0; ct < 8; ct++) {
                short8 bfr = *(const short8*)(Vs + (ct * 16 + lrow) * 72 + ks * 32 + quad * 8);
                acc[ct] = __builtin_amdgcn_mfma_f32_16x16x32_bf16(a, bfr, acc[ct], 0, 0, 0);
            }
        }
        __syncthreads();
    }
    int mv = gmask[b];
#pragma unroll
    for (int ct = 0; ct < 8; ct++)
#pragma unroll
        for (int r = 0; r < 4; r++) {
            int node = b * NB + rt * 64 + w * 16 + quad * 4 + r;
            int d = d0 + ct * 16 + lrow;
            out[(size_t)node * MD + d] = mv ? acc[ct][r] : 0.0f;
        }
}

// ---------------- launch -----------------------------------------------------
extern "C" void kernel_launch(void* const* d_in, const int* in_sizes, int n_in,
                              void* d_out, int out_size, void* d_ws, size_t ws_size,
                              hipStream_t stream) {
    (void)in_sizes; (void)n_in; (void)out_size; (void)ws_size;

    const float* X    = (const float*)d_in[0];
    const float* pos  = (const float*)d_in[1];
    const int*   gmask= (const int*)  d_in[3];
    const float* Wq   = (const float*)d_in[4];
    const float* bq   = (const float*)d_in[5];
    const float* Wk   = (const float*)d_in[6];
    const float* bk   = (const float*)d_in[7];
    const float* Wv   = (const float*)d_in[8];
    const float* bv   = (const float*)d_in[9];
    float* out = (float*)d_out;

    char* ws = (char*)d_ws;
    float2* csp = (float2*)(ws + OFF_CS);
    u16*   wt   = (u16*)  (ws + OFF_WT);
    u16*   qrp  = (u16*)  (ws + OFF_QR);
    u16*   krp  = (u16*)  (ws + OFF_KR);
    u16*   vtp  = (u16*)  (ws + OFF_VT);
    u16*   vbfp = (u16*)  (ws + OFF_VBF);
    u16*   App  = (u16*)  (ws + OFF_AP);
    u16*   Abfp = (u16*)  (ws + OFF_ABF);

    k_prep   <<<dim3(3072 + 36),   dim3(256),  0, stream>>>(pos, csp, Wq, Wk, Wv, wt);
    k_qkv    <<<dim3(64, 9),       dim3(256),  0, stream>>>(X, wt, bq, bk, bv, csp, qrp, krp, vbfp);
    k_transv <<<dim3(64, 18),      dim3(256),  0, stream>>>(vbfp, vtp);
    k_gemm1  <<<dim3(16, NSLICE),  dim3(1024), 0, stream>>>(qrp, krp, App);
    k_reduceA<<<dim3(512),         dim3(256),  0, stream>>>(App, Abfp);
    k_gemm2  <<<dim3(4, 9, 16),    dim3(256),  0, stream>>>(Abfp, vtp, gmask, out);
}